// Round 3
// baseline (837.088 us; speedup 1.0000x reference)
//
#include <hip/hip_runtime.h>
#include <math.h>

// ExpressiveUpdateRule: out[b,o,i] = W[b,o,i] - scale_b * (W[b,o,:]·x_b - g[b,o]) * x_b[i]
// scale_b = 1 / (LAMBDA_SQ + softplus(x_b·eta_w + eta_b))
// B=128, D=1024, fp32. Ideal traffic: 512 MiB read (W) + 512 MiB write -> ~180 us floor.
// R2: single fused dispatch (scale recomputed per wave under load latency).
// R3: persistent blocks (grid=1024, 4 resident/CU) looping 16 row-tiles with a
//     cross-tile register double-buffer: tile t+1's loads issue BEFORE tile t's
//     reduce/store chain -> load pipe never drains (breaks the phase-locked
//     load/reduce/store convoy that capped R0-R2 at ~50% of stream BW).

typedef float f4 __attribute__((ext_vector_type(4)));

constexpr int D = 1024;
constexpr float LAMBDA_SQ = 1024.0f;
constexpr int WAVES = 4;
constexpr int ROWS_PER_WAVE = 2;                        // per tile-iteration
constexpr int ROWS_PER_ITER = WAVES * ROWS_PER_WAVE;    // 8 rows / block / iter
constexpr int BLOCKS_PER_BATCH = 8;
constexpr int ROWS_PER_BLOCK = D / BLOCKS_PER_BATCH;    // 128 contiguous rows
constexpr int NIT = ROWS_PER_BLOCK / ROWS_PER_ITER;     // 16 tile-iterations

__global__ __launch_bounds__(256, 4) void update_kernel(const float* __restrict__ W,
                                                        const float* __restrict__ x,
                                                        const float* __restrict__ g,
                                                        const float* __restrict__ eta_w,
                                                        const float* __restrict__ eta_b,
                                                        float* __restrict__ out) {
    const int tid  = threadIdx.x;
    const int b    = blockIdx.x / BLOCKS_PER_BATCH;
    const int blk  = blockIdx.x % BLOCKS_PER_BATCH;
    const int wave = tid >> 6;
    const int lane = tid & 63;
    const int span = blk * ROWS_PER_BLOCK;              // this block: rows span..span+127

    const float* __restrict__ Wb = W   + (size_t)b * D * D;
    float*       __restrict__ Ob = out + (size_t)b * D * D;
    const float* __restrict__ gb = g   + (size_t)b * D;

    // x[b,:] into regs (reused every tile); eta_w transient (dead after scale)
    const f4* __restrict__ xv = (const f4*)(x + (size_t)b * D);
    f4 xreg[4];
    #pragma unroll
    for (int c = 0; c < 4; ++c) xreg[c] = xv[c * 64 + lane];

    const f4* __restrict__ ev = (const f4*)eta_w;
    f4 ereg[4];
    #pragma unroll
    for (int c = 0; c < 4; ++c) ereg[c] = ev[c * 64 + lane];
    const float eb = eta_b[0];

    // ---- cross-tile double buffer ----
    f4 bufA[ROWS_PER_WAVE][4], bufB[ROWS_PER_WAVE][4];
    float gA[ROWS_PER_WAVE], gB[ROWS_PER_WAVE];

    auto prefetch = [&](f4 (&buf)[ROWS_PER_WAVE][4], float (&gv)[ROWS_PER_WAVE], int t) {
        const int row = span + t * ROWS_PER_ITER + wave * ROWS_PER_WAVE;
        const f4* __restrict__ src = (const f4*)(Wb + (size_t)row * D);
        #pragma unroll
        for (int r = 0; r < ROWS_PER_WAVE; ++r) {
            #pragma unroll
            for (int c = 0; c < 4; ++c)
                buf[r][c] = __builtin_nontemporal_load(&src[r * (D / 4) + c * 64 + lane]);
        }
        #pragma unroll
        for (int r = 0; r < ROWS_PER_WAVE; ++r) gv[r] = gb[row + r];  // broadcast
    };

    // issue tile 0's loads before computing scale (scale math hides under them)
    prefetch(bufA, gA, 0);

    // ---- scale: 1/(LAMBDA_SQ + softplus(x.eta_w + eta_b)), per-wave recompute ----
    float p = 0.0f;
    #pragma unroll
    for (int c = 0; c < 4; ++c) {
        p += ereg[c].x * xreg[c].x + ereg[c].y * xreg[c].y
           + ereg[c].z * xreg[c].z + ereg[c].w * xreg[c].w;
    }
    #pragma unroll
    for (int off = 32; off > 0; off >>= 1) p += __shfl_xor(p, off);
    const float z = p + eb;
    const float sp = fmaxf(z, 0.0f) + log1pf(expf(-fabsf(z)));   // stable softplus
    const float s = 1.0f / (LAMBDA_SQ + sp);

    auto compute = [&](f4 (&buf)[ROWS_PER_WAVE][4], float (&gv)[ROWS_PER_WAVE], int t) {
        const int row = span + t * ROWS_PER_ITER + wave * ROWS_PER_WAVE;
        float dot[ROWS_PER_WAVE];
        #pragma unroll
        for (int r = 0; r < ROWS_PER_WAVE; ++r) {
            float d = 0.0f;
            #pragma unroll
            for (int c = 0; c < 4; ++c) {
                d += buf[r][c].x * xreg[c].x + buf[r][c].y * xreg[c].y
                   + buf[r][c].z * xreg[c].z + buf[r][c].w * xreg[c].w;
            }
            dot[r] = d;
        }
        #pragma unroll
        for (int off = 32; off > 0; off >>= 1) {
            #pragma unroll
            for (int r = 0; r < ROWS_PER_WAVE; ++r) dot[r] += __shfl_xor(dot[r], off);
        }
        f4* __restrict__ dst = (f4*)(Ob + (size_t)row * D);
        #pragma unroll
        for (int r = 0; r < ROWS_PER_WAVE; ++r) {
            const float f = s * (dot[r] - gv[r]);
            #pragma unroll
            for (int c = 0; c < 4; ++c) {
                f4 o;
                o.x = buf[r][c].x - f * xreg[c].x;
                o.y = buf[r][c].y - f * xreg[c].y;
                o.z = buf[r][c].z - f * xreg[c].z;
                o.w = buf[r][c].w - f * xreg[c].w;
                __builtin_nontemporal_store(o, &dst[r * (D / 4) + c * 64 + lane]);
            }
        }
    };

    // ping-pong over 16 tiles; named buffers -> all indices compile-time
    #pragma unroll
    for (int it2 = 0; it2 < NIT / 2; ++it2) {
        const int tA = 2 * it2, tB = 2 * it2 + 1;
        prefetch(bufB, gB, tB);            // issue t+1 loads BEFORE t's reduce/store
        compute(bufA, gA, tA);
        if (tB + 1 < NIT) prefetch(bufA, gA, tB + 1);
        compute(bufB, gB, tB);
    }
}

extern "C" void kernel_launch(void* const* d_in, const int* in_sizes, int n_in,
                              void* d_out, int out_size, void* d_ws, size_t ws_size,
                              hipStream_t stream) {
    const float* W     = (const float*)d_in[0];
    const float* x     = (const float*)d_in[1];
    const float* g     = (const float*)d_in[2];
    const float* eta_w = (const float*)d_in[3];
    const float* eta_b = (const float*)d_in[4];
    float* out = (float*)d_out;

    const int B = in_sizes[1] / D;  // 128
    update_kernel<<<B * BLOCKS_PER_BATCH, 256, 0, stream>>>(W, x, g, eta_w, eta_b, out);
}